// Round 8
// baseline (294.262 us; speedup 1.0000x reference)
//
#include <hip/hip_runtime.h>

// 2-layer GRU (B=4096, S=512, IN=4, H=32) + FC(32->32) + FC(32->1), fp32 in/out.
// 4 waves/block = {M0: L0 recurrence, M1: L1 recurrence, H0: x-preacts, H1:
// Wih1*h1 preacts}; 256 blocks x 16 batch. LANE-LOCAL recurrence (R4 mapping):
// tile j=2G+s, A-row c -> W row 32G+8*(c>>2)+4s+(c&3), so D-row 4q+r = unit
// 8q+4s+r = lane's own next-step B-frag element -> h never leaves registers.
// Helpers write per-step preacts (AX, D-layout) one step ahead; mains use them
// as MFMA C-operands. Numerics = R7 (W hi/lo exact, state bf16-hi, x exact).
// Lags: M0 step i @ iter i; H1 makes AX1[step i-1] @ iter i; M1 step i-2 @ i.

#define SEQ 512
#define LOG2E 1.44269504088896340736f

typedef __attribute__((ext_vector_type(8))) short  short8;
typedef __attribute__((ext_vector_type(4))) float  f32x4;
typedef __attribute__((ext_vector_type(4))) unsigned uint4v;

static __device__ __forceinline__ unsigned short f2bf(float f) {
    unsigned u = __builtin_bit_cast(unsigned, f);
    return (unsigned short)((u + 0x7fffu + ((u >> 16) & 1u)) >> 16);
}
static __device__ __forceinline__ float bf2f(unsigned short b) {
    return __builtin_bit_cast(float, ((unsigned)b) << 16);
}
static __device__ __forceinline__ unsigned cvtpk(float a, float b) {
    unsigned r;
    asm("v_cvt_pk_bf16_f32 %0, %1, %2" : "=v"(r) : "v"(a), "v"(b));
    return r;
}
static __device__ __forceinline__ float sigm(float x) {
    return __builtin_amdgcn_rcpf(1.0f + __builtin_amdgcn_exp2f(-LOG2E * x));
}
static __device__ __forceinline__ float tanh_(float x) {
    return 1.0f - 2.0f * __builtin_amdgcn_rcpf(1.0f + __builtin_amdgcn_exp2f((2.0f * LOG2E) * x));
}

#define MFMA(A, B, C) __builtin_amdgcn_mfma_f32_16x16x32_bf16((A), (B), (C), 0, 0, 0)

// (Whi + Wlo) * B + Cin, chained accumulate (2 MFMAs, depth 2)
static __device__ __forceinline__ f32x4 side2(short8 Wh, short8 Wl, short8 B,
                                              f32x4 Cin) {
    f32x4 a = MFMA(Wh, B, Cin);
    a = MFMA(Wl, B, a);
    return a;
}

static __device__ __forceinline__ void cvt8(const float* p, short8& h8, short8& l8) {
    f32x4 v0 = *(const f32x4*)p;
    f32x4 v1 = *(const f32x4*)(p + 4);
#pragma unroll
    for (int e = 0; e < 8; ++e) {
        float v = (e < 4) ? v0[e] : v1[e - 4];
        unsigned short hb = f2bf(v);
        h8[e] = (short)hb;
        l8[e] = (short)f2bf(v - bf2f(hb));
    }
}

__global__ __launch_bounds__(256, 1) void gru_fused(
    const float* __restrict__ x,
    const float* __restrict__ Wih0, const float* __restrict__ Whh0,
    const float* __restrict__ bih0, const float* __restrict__ bhh0,
    const float* __restrict__ Wih1, const float* __restrict__ Whh1,
    const float* __restrict__ bih1, const float* __restrict__ bhh1,
    const float* __restrict__ Wfc2, const float* __restrict__ bfc2,
    const float* __restrict__ Wfc,  const float* __restrict__ bfc,
    float* __restrict__ out)
{
    const int tid  = threadIdx.x;
    const int lane = tid & 63;
    const int wid  = tid >> 6;      // 0=M0(L0 main) 1=M1(L1 main) 2=H0 3=H1
    const int c    = lane & 15;     // batch col
    const int q    = lane >> 4;     // 0..3
    const int b0   = blockIdx.x * 16;

    // LDS: ST01 h1-frag handoff: 2 bufs x 64 lanes x 16B = 2048
    //      XS   x ring: 32 steps x 16 rows x 16B          = 8192
    //      AX0  L0 preacts: 2 bufs x 6 tiles x 64 x 16B   = 12288
    //      AX1  L1 preacts: same                          = 12288
    __shared__ __align__(16) char smem[34816];
    uint4v* ST01 = (uint4v*)smem;                // [buf*64 + lane]
    f32x4*  XS   = (f32x4*)(smem + 2048);        // [step*16 + row]
    f32x4*  AX0  = (f32x4*)(smem + 10240);       // [buf*384 + j*64 + lane]
    f32x4*  AX1  = (f32x4*)(smem + 22528);

    // zero the h1 handoff buffers
    if (tid < 128) ST01[tid] = (uint4v){0, 0, 0, 0};

    // prologue: stage x steps 0..31 (all 256 threads, 2 entries each)
#pragma unroll
    for (int k = 0; k < 2; ++k) {
        const int e = tid + 256 * k;             // 0..511 = 32 steps x 16 rows
        const int step = e >> 4, row = e & 15;
        XS[e] = *(const f32x4*)(x + ((long)(b0 + row) * SEQ + step) * 4);
    }

    // ---------------- per-role weight setup (wave-uniform) ----------------
    // tile j = 2G+s (G: 0=r,1=z,2=n). A-row c -> W row 32G + 8*(c>>2)+4s+(c&3)
    short8 wh[6], wl[6];      // mains: Whh hi/lo   | H1: Wih1 hi/lo
    f32x4  bcin[6];           // mains: [4],[5]=bhh n-slices | H1: folded biases
    f32x4  wx[24];            // H0: Wih0 rows fp32
    float  bxs[24];           // H0: folded biases

    if (wid < 2) {
        const float* Whp = wid ? Whh1 : Whh0;
        const float* bhp = wid ? bhh1 : bhh0;
#pragma unroll
        for (int j = 0; j < 6; ++j) {
            const int G = j >> 1, s = j & 1;
            const int rowA = 32 * G + 8 * (c >> 2) + 4 * s + (c & 3);
            cvt8(Whp + rowA * 32 + 8 * q, wh[j], wl[j]);
        }
#pragma unroll
        for (int s = 0; s < 2; ++s)
            bcin[4 + s] = *(const f32x4*)(bhp + 64 + 8 * q + 4 * s);
    } else if (wid == 3) {
#pragma unroll
        for (int j = 0; j < 6; ++j) {
            const int G = j >> 1, s = j & 1;
            const int rowA = 32 * G + 8 * (c >> 2) + 4 * s + (c & 3);
            cvt8(Wih1 + rowA * 32 + 8 * q, wh[j], wl[j]);
            const int bb = 32 * G + 8 * q + 4 * s;
            f32x4 b = *(const f32x4*)(bih1 + bb);
            if (G < 2) b += *(const f32x4*)(bhh1 + bb);
            bcin[j] = b;
        }
    } else {  // H0
#pragma unroll
        for (int j = 0; j < 6; ++j)
#pragma unroll
            for (int r = 0; r < 4; ++r) {
                const int G = j >> 1, s = j & 1;
                const int g = 32 * G + 8 * q + 4 * s + r;
                wx[4 * j + r]  = *(const f32x4*)(Wih0 + g * 4);
                bxs[4 * j + r] = bih0[g] + ((G < 2) ? bhh0[g] : 0.0f);
            }
        // AX0[buf0] = preacts for step 0 (direct global x read)
        f32x4 xv = *(const f32x4*)(x + (long)(b0 + c) * (SEQ * 4));
#pragma unroll
        for (int j = 0; j < 6; ++j) {
            f32x4 a;
#pragma unroll
            for (int r = 0; r < 4; ++r) {
                f32x4 w = wx[4 * j + r];
                a[r] = bxs[4 * j + r] + w[0] * xv[0] + w[1] * xv[1]
                     + w[2] * xv[2] + w[3] * xv[3];
            }
            AX0[j * 64 + lane] = a;
        }
    }

    // mains' recurrent state: bf16-hi B-frag + fp32 master (units 8q+4s+r)
    uint4v sfrag = {0, 0, 0, 0};
    float  hm[2][4] = {{0, 0, 0, 0}, {0, 0, 0, 0}};

    __syncthreads();

    // ---------------- main loop: 514 iterations ----------------
    // M0 @ iter i: step i (i<SEQ): C-in AX0[i&1]; publish frag -> ST01[i&1].
    // H0 @ iter i: AX0 for step i+1 -> AX0[(i+1)&1]; stage x 16 ahead.
    // H1 @ iter i (1<=i<=SEQ): read ST01[(i+1)&1] (=h1[i-1]),
    //                          AX1 for step i-1 -> AX1[(i+1)&1].
    // M1 @ iter i (i>=2): step i-2: C-in AX1[i&1] (matching-step input).
#pragma unroll 2
    for (int i = 0; i <= SEQ + 1; ++i) {
        if (wid < 2) {
            const bool act = (wid == 0) ? (i < SEQ) : (i >= 2);
            if (act) {
                const f32x4* axb = (wid == 0) ? (AX0 + (i & 1) * 384)
                                              : (AX1 + (i & 1) * 384);
                const short8 B = __builtin_bit_cast(short8, sfrag);
                f32x4 ax[6];
#pragma unroll
                for (int j = 0; j < 6; ++j) ax[j] = axb[j * 64 + lane];

                // n tiles first (reg C-in, start while ax reads land)
                f32x4 p4 = side2(wh[4], wl[4], B, bcin[4]);
                f32x4 p5 = side2(wh[5], wl[5], B, bcin[5]);
                f32x4 p0 = side2(wh[0], wl[0], B, ax[0]);
                f32x4 p1 = side2(wh[1], wl[1], B, ax[1]);
                f32x4 p2 = side2(wh[2], wl[2], B, ax[2]);
                f32x4 p3 = side2(wh[3], wl[3], B, ax[3]);

                float hv[2][4];
#pragma unroll
                for (int s = 0; s < 2; ++s) {
                    const f32x4 pr  = s ? p1 : p0;
                    const f32x4 pz  = s ? p3 : p2;
                    const f32x4 pn  = s ? p5 : p4;
                    const f32x4 axn = s ? ax[5] : ax[4];
#pragma unroll
                    for (int r = 0; r < 4; ++r) {
                        float rg = sigm(pr[r]);
                        float zg = sigm(pz[r]);
                        float ng = tanh_(axn[r] + rg * pn[r]);
                        float hN = ng + zg * (hm[s][r] - ng);
                        hm[s][r] = hN;
                        hv[s][r] = hN;
                    }
                }
                // pack next-step B-frag: e<4 <- s=0 (r=e), e>=4 <- s=1
                unsigned w0 = cvtpk(hv[0][0], hv[0][1]);
                unsigned w1 = cvtpk(hv[0][2], hv[0][3]);
                unsigned w2 = cvtpk(hv[1][0], hv[1][1]);
                unsigned w3 = cvtpk(hv[1][2], hv[1][3]);
                uint4v ns = {w0, w1, w2, w3};
                sfrag = ns;
                if (wid == 0) ST01[(i & 1) * 64 + lane] = sfrag;  // h1[i]
            }
        } else if (wid == 2) {
            // ---- x staging: 16 steps, 16 iterations ahead ----
            if ((i & 15) == 0) {
                const int base = i + 16;
                if (base < SEQ) {
                    const int row = lane & 15, so = lane >> 4;   // so 0..3
#pragma unroll
                    for (int k = 0; k < 4; ++k) {
                        const int step = base + so + 4 * k;
                        XS[(step & 31) * 16 + row] =
                            *(const f32x4*)(x + ((long)(b0 + row) * SEQ + step) * 4);
                    }
                }
            }
            // ---- AX0 for step i+1 (exact fp32 x-matvec) ----
            const int step = i + 1;
            if (step < SEQ) {
                f32x4 xv = XS[(step & 31) * 16 + c];
                f32x4* dst = AX0 + (step & 1) * 384;
#pragma unroll
                for (int j = 0; j < 6; ++j) {
                    f32x4 a;
#pragma unroll
                    for (int r = 0; r < 4; ++r) {
                        f32x4 w = wx[4 * j + r];
                        a[r] = bxs[4 * j + r] + w[0] * xv[0] + w[1] * xv[1]
                             + w[2] * xv[2] + w[3] * xv[3];
                    }
                    dst[j * 64 + lane] = a;
                }
            }
        } else {
            // ---- H1: AX1 for step i-1 = Wih1*h1[i-1] + folded biases ----
            if (i >= 1 && i <= SEQ) {
                const short8 uf = __builtin_bit_cast(short8,
                                      ST01[((i + 1) & 1) * 64 + lane]);
                f32x4* dst = AX1 + ((i + 1) & 1) * 384;
#pragma unroll
                for (int j = 0; j < 6; ++j)
                    dst[j * 64 + lane] = side2(wh[j], wl[j], uf, bcin[j]);
            }
        }
        __syncthreads();
    }

    // ---------------- epilogue: out[b] = Weff . h2[b] + cst ----------------
    if (wid == 1) {
        float acc = 0.0f;
#pragma unroll
        for (int s = 0; s < 2; ++s)
#pragma unroll
            for (int r = 0; r < 4; ++r) {
                const int u = 8 * q + 4 * s + r;
                float we = 0.0f;
                for (int j = 0; j < 32; ++j)
                    we += Wfc[j] * Wfc2[j * 32 + u];
                acc += we * hm[s][r];
            }
        acc += __shfl_xor(acc, 16);
        acc += __shfl_xor(acc, 32);
        if (q == 0) {
            float cst = bfc[0];
            for (int j = 0; j < 32; ++j) cst += Wfc[j] * bfc2[j];
            out[b0 + c] = acc + cst;
        }
    }
}

extern "C" void kernel_launch(void* const* d_in, const int* in_sizes, int n_in,
                              void* d_out, int out_size, void* d_ws, size_t ws_size,
                              hipStream_t stream) {
    const float* x    = (const float*)d_in[0];
    const float* Wih0 = (const float*)d_in[1];
    const float* Whh0 = (const float*)d_in[2];
    const float* bih0 = (const float*)d_in[3];
    const float* bhh0 = (const float*)d_in[4];
    const float* Wih1 = (const float*)d_in[5];
    const float* Whh1 = (const float*)d_in[6];
    const float* bih1 = (const float*)d_in[7];
    const float* bhh1 = (const float*)d_in[8];
    const float* Wfc2 = (const float*)d_in[9];
    const float* bfc2 = (const float*)d_in[10];
    const float* Wfc  = (const float*)d_in[11];
    const float* bfc  = (const float*)d_in[12];

    const int nblocks = out_size / 16;  // 4096/16 = 256
    hipLaunchKernelGGL(gru_fused, dim3(nblocks), dim3(256), 0, stream,
                       x, Wih0, Whh0, bih0, bhh0, Wih1, Whh1, bih1, bhh1,
                       Wfc2, bfc2, Wfc, bfc, (float*)d_out);
}

// Round 9
// 234.635 us; speedup vs baseline: 1.2541x; 1.2541x over previous
//
#include <hip/hip_runtime.h>

// 2-layer GRU (B=4096, S=512, IN=4, H=32) + FC(32->32) + FC(32->1), fp32 in/out.
// 6 waves/block: mains wid0-3 = (L, hf) on SIMD0-3; merged helpers wid4,5 (hf)
// on SIMD0,1. Helpers produce feed-forward preacts ahead of time into LDS:
//   AX0[step] = bih0+bhh0(r,z)+Wih0*x[step] (exact fp32); AX1 = Wih1*h1+biases.
// Mains run the pure recurrence: 6 MFMA (Whh hi/lo x state-bf16, C-in = AX)
// -> gates -> pack -> LDS publish, s_setprio(1) during compute.
// Lags (verified R7): M0 step i @ iter i; helper makes AX0[i+1], AX1 for step
// i-1 @ iter i; M1 step i-2 @ iter i. 514 iterations, one barrier each.
// Numerics = R7 (weights hi/lo exact, state bf16-hi, x-side exact fp32).

#define SEQ 512
#define LOG2E 1.44269504088896340736f

typedef __attribute__((ext_vector_type(8))) short  short8;
typedef __attribute__((ext_vector_type(4))) float  f32x4;
typedef __attribute__((ext_vector_type(2))) unsigned uint2v;

static __device__ __forceinline__ unsigned short f2bf(float f) {
    unsigned u = __builtin_bit_cast(unsigned, f);
    return (unsigned short)((u + 0x7fffu + ((u >> 16) & 1u)) >> 16);
}
static __device__ __forceinline__ float bf2f(unsigned short b) {
    return __builtin_bit_cast(float, ((unsigned)b) << 16);
}
static __device__ __forceinline__ unsigned cvtpk(float a, float b) {
    unsigned r;
    asm("v_cvt_pk_bf16_f32 %0, %1, %2" : "=v"(r) : "v"(a), "v"(b));
    return r;
}
static __device__ __forceinline__ float sigm(float x) {
    return __builtin_amdgcn_rcpf(1.0f + __builtin_amdgcn_exp2f(-LOG2E * x));
}
static __device__ __forceinline__ float tanh_(float x) {
    return 1.0f - 2.0f * __builtin_amdgcn_rcpf(1.0f + __builtin_amdgcn_exp2f((2.0f * LOG2E) * x));
}

#define MFMA(A, B, C) __builtin_amdgcn_mfma_f32_16x16x32_bf16((A), (B), (C), 0, 0, 0)

// (Whi + Wlo) * B + Cin, chained accumulate (2 MFMAs, depth 2)
static __device__ __forceinline__ f32x4 side2(short8 Wh, short8 Wl, short8 B,
                                              f32x4 Cin) {
    f32x4 a = MFMA(Wh, B, Cin);
    a = MFMA(Wl, B, a);
    return a;
}

static __device__ __forceinline__ void cvt8(const float* p, short8& h8, short8& l8) {
    f32x4 v0 = *(const f32x4*)p;
    f32x4 v1 = *(const f32x4*)(p + 4);
#pragma unroll
    for (int e = 0; e < 8; ++e) {
        float v = (e < 4) ? v0[e] : v1[e - 4];
        unsigned short hb = f2bf(v);
        h8[e] = (short)hb;
        l8[e] = (short)f2bf(v - bf2f(hb));
    }
}

__global__ __launch_bounds__(384, 1) void gru_fused(
    const float* __restrict__ x,
    const float* __restrict__ Wih0, const float* __restrict__ Whh0,
    const float* __restrict__ bih0, const float* __restrict__ bhh0,
    const float* __restrict__ Wih1, const float* __restrict__ Whh1,
    const float* __restrict__ bih1, const float* __restrict__ bhh1,
    const float* __restrict__ Wfc2, const float* __restrict__ bfc2,
    const float* __restrict__ Wfc,  const float* __restrict__ bfc,
    float* __restrict__ out)
{
    const int tid  = threadIdx.x;
    const int lane = tid & 63;
    const int wid  = tid >> 6;          // 0..5; SIMD = wid & 3
    const bool isMain = (wid < 4);      // 0..3 mains, 4..5 merged helpers
    const int L    = (wid >> 1) & 1;    // mains: layer
    const int hf   = wid & 1;           // unit half (mains & helpers)
    const int c    = lane & 15;         // batch col
    const int q    = lane >> 4;         // 0..3
    const int b0   = blockIdx.x * 16;

    // LDS map (identical to R7):
    //  ST01: h1 frags, 2 bufs x [16][80B] = 2560
    //  ST2 : h2 frags, 2 bufs x [16][80B] = 2560
    //  XS  : x ring, 32 steps x 16 x 16B  = 8192
    //  AX0 : 2 bufs x 6 tiles x 64 x 16B  = 12288
    //  AX1 : same                         = 12288
    //  EP  : epilogue scratch             = 128
    __shared__ __align__(16) char smem[38016];
    char*  ST01 = smem;
    char*  ST2  = smem + 2560;
    f32x4* XS   = (f32x4*)(smem + 5120);
    f32x4* AX0  = (f32x4*)(smem + 13312);
    f32x4* AX1  = (f32x4*)(smem + 25600);
    float* EP   = (float*)(smem + 37888);

    // zero state buffers (h = 0)
    for (int i = tid; i < 1280; i += 384) ((unsigned*)smem)[i] = 0u;

    // prologue: stage x steps 0..31 (512 f32x4 entries over 384 threads)
    for (int e = tid; e < 512; e += 384) {
        const int step = e >> 4, row = e & 15;
        XS[e] = *(const f32x4*)(x + ((long)(b0 + row) * SEQ + step) * 4);
    }

    const int tts[3] = {hf, 2 + hf, 4 + hf};   // r,z,n tiles for this half

    // ------------- per-role weight setup (wave-uniform branches) -----------
    short8 whh_[3], whl_[3];            // mains: Whh hi/lo
    f32x4  bhv2 = {0, 0, 0, 0};        // mains: bhh n-slice (C-in for j=2)
    f32x4  wx[12];                      // helpers: Wih0 rows fp32
    float  bxs[12];                     // helpers: folded L0 biases
    short8 wuh[3], wul[3];              // helpers: Wih1 hi/lo
    f32x4  bxv[3];                      // helpers: folded L1 biases

    if (isMain) {
        const float* Whp = L ? Whh1 : Whh0;
        const float* bhp = L ? bhh1 : bhh0;
#pragma unroll
        for (int j = 0; j < 3; ++j)
            cvt8(Whp + (16 * tts[j] + c) * 32 + 8 * q, whh_[j], whl_[j]);
        bhv2 = *(const f32x4*)(bhp + 16 * tts[2] + 4 * q);
    } else {
#pragma unroll
        for (int j = 0; j < 3; ++j)
#pragma unroll
            for (int r = 0; r < 4; ++r) {
                const int g = 16 * tts[j] + 4 * q + r;
                wx[4 * j + r]  = *(const f32x4*)(Wih0 + g * 4);
                bxs[4 * j + r] = bih0[g] + ((j < 2) ? bhh0[g] : 0.0f);
            }
#pragma unroll
        for (int j = 0; j < 3; ++j) {
            cvt8(Wih1 + (16 * tts[j] + c) * 32 + 8 * q, wuh[j], wul[j]);
            f32x4 bb = *(const f32x4*)(bih1 + 16 * tts[j] + 4 * q);
            if (j < 2) bb += *(const f32x4*)(bhh1 + 16 * tts[j] + 4 * q);
            bxv[j] = bb;
        }
        // prologue: AX0 buf0 = preacts for step 0 (direct global x read)
        f32x4 xv = *(const f32x4*)(x + (long)(b0 + c) * (SEQ * 4));
#pragma unroll
        for (int j = 0; j < 3; ++j) {
            f32x4 a;
#pragma unroll
            for (int r = 0; r < 4; ++r) {
                f32x4 w = wx[4 * j + r];
                a[r] = bxs[4 * j + r] + w[0] * xv[0] + w[1] * xv[1]
                     + w[2] * xv[2] + w[3] * xv[3];
            }
            AX0[tts[j] * 64 + q * 16 + c] = a;
        }
    }

    float hst[4] = {0, 0, 0, 0};   // mains: units 16hf+4q+r, batch c
    const int frag_off = c * 80 + q * 16;                 // b128 B-frag read
    const int wr_off   = c * 80 + (16 * hf + 4 * q) * 2;  // b64 D write (hi)

    __syncthreads();

    // ---------------- pipelined main loop: 514 iterations ----------------
    // (lag structure identical to R7 — verified)
#pragma unroll 2
    for (int i = 0; i <= SEQ + 1; ++i) {
        if (isMain) {
            const bool act = (L == 0) ? (i < SEQ) : (i >= 2);
            if (act) {
                __builtin_amdgcn_s_setprio(1);
                const char*  st;
                const f32x4* axb;
                char*        dst;
                if (L == 0) {
                    st  = ST01 + ((i + 1) & 1) * 1280;
                    axb = AX0 + (i & 1) * 384;
                    dst = ST01 + (i & 1) * 1280;
                } else {
                    st  = ST2 + ((i + 1) & 1) * 1280;
                    axb = AX1 + ((i + 1) & 1) * 384;
                    dst = ST2 + (i & 1) * 1280;
                }
                short8 sfrag = *(const short8*)(st + frag_off);
                f32x4 ax0v = axb[tts[0] * 64 + q * 16 + c];
                f32x4 ax1v = axb[tts[1] * 64 + q * 16 + c];
                f32x4 ax2v = axb[tts[2] * 64 + q * 16 + c];

                // n-gate chain first: register C-in, starts as soon as sfrag lands
                f32x4 p2 = side2(whh_[2], whl_[2], sfrag, bhv2);
                f32x4 p0 = side2(whh_[0], whl_[0], sfrag, ax0v);
                f32x4 p1 = side2(whh_[1], whl_[1], sfrag, ax1v);

                float hv[4];
#pragma unroll
                for (int r = 0; r < 4; ++r) {
                    float rg = sigm(p0[r]);
                    float zg = sigm(p1[r]);
                    float ng = tanh_(ax2v[r] + rg * p2[r]);
                    float hN = ng + zg * (hst[r] - ng);
                    hst[r] = hN;
                    hv[r] = hN;
                }
                unsigned w0 = cvtpk(hv[0], hv[1]);
                unsigned w1 = cvtpk(hv[2], hv[3]);
                uint2v wpk = {w0, w1};
                *(uint2v*)(dst + wr_off) = wpk;
                __builtin_amdgcn_s_setprio(0);
            }
        } else {
            // ---- x staging: 8 steps every 8 iters, >=16 iters ahead ----
            if ((i & 7) == 0) {
                const int base = i + 16;
                if (base < SEQ) {
                    const int idx = (wid - 4) * 64 + lane;   // 0..127
                    const int step = base + (idx >> 4), row = idx & 15;
                    XS[(step & 31) * 16 + row] =
                        *(const f32x4*)(x + ((long)(b0 + row) * SEQ + step) * 4);
                }
            }
            // ---- AX1 for step i-1 = Wih1*h1[i-1] + folded biases ----
            if (i >= 1 && i <= SEQ) {
                const char* us = ST01 + ((i + 1) & 1) * 1280;   // h1[i-1]
                short8 uf = *(const short8*)(us + frag_off);
                f32x4* dstax = AX1 + (i & 1) * 384;
#pragma unroll
                for (int j = 0; j < 3; ++j)
                    dstax[tts[j] * 64 + q * 16 + c] =
                        side2(wuh[j], wul[j], uf, bxv[j]);
            }
            // ---- AX0 for step i+1 (exact fp32 x-matvec) ----
            const int stp = i + 1;
            if (stp < SEQ) {
                f32x4 xv = XS[(stp & 31) * 16 + c];
                f32x4* dstax = AX0 + (stp & 1) * 384;
#pragma unroll
                for (int j = 0; j < 3; ++j) {
                    f32x4 a;
#pragma unroll
                    for (int r = 0; r < 4; ++r) {
                        f32x4 w = wx[4 * j + r];
                        a[r] = bxs[4 * j + r] + w[0] * xv[0] + w[1] * xv[1]
                             + w[2] * xv[2] + w[3] * xv[3];
                    }
                    dstax[tts[j] * 64 + q * 16 + c] = a;
                }
            }
        }
        __syncthreads();
    }

    // ---------------- epilogue: out = Weff . h2 + cst ----------------
    if (isMain && L == 1) {
        float we[4] = {0, 0, 0, 0};
        const float* w2p = Wfc2 + 16 * hf + 4 * q;
#pragma unroll 8
        for (int j = 0; j < 32; ++j) {
            float wf = Wfc[j];
            f32x4 w2 = *(const f32x4*)(w2p + j * 32);
#pragma unroll
            for (int r = 0; r < 4; ++r) we[r] += wf * w2[r];
        }
        float acc = we[0] * hst[0] + we[1] * hst[1] + we[2] * hst[2] + we[3] * hst[3];
        acc += __shfl_xor(acc, 16);
        acc += __shfl_xor(acc, 32);
        if (q == 0) EP[hf * 16 + c] = acc;
    }
    __syncthreads();
    if (wid == 0 && q == 0) {
        float cst = bfc[0];
        for (int j = 0; j < 32; ++j) cst += Wfc[j] * bfc2[j];
        out[b0 + c] = EP[c] + EP[16 + c] + cst;
    }
}

extern "C" void kernel_launch(void* const* d_in, const int* in_sizes, int n_in,
                              void* d_out, int out_size, void* d_ws, size_t ws_size,
                              hipStream_t stream) {
    const float* x    = (const float*)d_in[0];
    const float* Wih0 = (const float*)d_in[1];
    const float* Whh0 = (const float*)d_in[2];
    const float* bih0 = (const float*)d_in[3];
    const float* bhh0 = (const float*)d_in[4];
    const float* Wih1 = (const float*)d_in[5];
    const float* Whh1 = (const float*)d_in[6];
    const float* bih1 = (const float*)d_in[7];
    const float* bhh1 = (const float*)d_in[8];
    const float* Wfc2 = (const float*)d_in[9];
    const float* bfc2 = (const float*)d_in[10];
    const float* Wfc  = (const float*)d_in[11];
    const float* bfc  = (const float*)d_in[12];

    const int nblocks = out_size / 16;  // 4096/16 = 256
    hipLaunchKernelGGL(gru_fused, dim3(nblocks), dim3(384), 0, stream,
                       x, Wih0, Whh0, bih0, bhh0, Wih1, Whh1, bih1, bhh1,
                       Wfc2, bfc2, Wfc, bfc, (float*)d_out);
}

// Round 10
// 211.271 us; speedup vs baseline: 1.3928x; 1.1106x over previous
//
#include <hip/hip_runtime.h>

// 2-layer GRU (B=4096, S=512, IN=4, H=32) + FC(32->32) + FC(32->1), fp32 in/out.
// R7 structure (best: 221us): 8 waves/block = (role: main/helper) x (layer) x
// (unit-half hf); main+helper paired per SIMD. Helpers produce feed-forward
// preacts one step ahead into LDS (AX); mains run the pure recurrence
// (6 MFMA Whh hi/lo x state-bf16, C-in = AX preacts) -> gates -> pack.
// R10 changes (scheduling only, numerics bit-identical to R7):
//  1) main-loop barrier = s_waitcnt lgkmcnt(0); s_barrier  (no vmcnt drain ->
//     helper HBM prefetch stays in flight across barriers)
//  2) T14 split x-staging: global_load at (i&15)==0 into regs, ds_write at
//     (i&15)==8 (HBM latency hidden under 8 iterations of compute).
// Lags (verified R7): M0 step i @ iter i; H1 makes AX1[step i-1] @ iter i;
// M1 step i-2 @ iter i; 514 iterations.

#define SEQ 512
#define LOG2E 1.44269504088896340736f

// lgkm-only barrier: orders LDS producer->consumer without draining vmcnt
#define BSYNC() asm volatile("s_waitcnt lgkmcnt(0)\ns_barrier" ::: "memory")

typedef __attribute__((ext_vector_type(8))) short  short8;
typedef __attribute__((ext_vector_type(4))) float  f32x4;
typedef __attribute__((ext_vector_type(2))) unsigned uint2v;

static __device__ __forceinline__ unsigned short f2bf(float f) {
    unsigned u = __builtin_bit_cast(unsigned, f);
    return (unsigned short)((u + 0x7fffu + ((u >> 16) & 1u)) >> 16);
}
static __device__ __forceinline__ float bf2f(unsigned short b) {
    return __builtin_bit_cast(float, ((unsigned)b) << 16);
}
static __device__ __forceinline__ unsigned cvtpk(float a, float b) {
    unsigned r;
    asm("v_cvt_pk_bf16_f32 %0, %1, %2" : "=v"(r) : "v"(a), "v"(b));
    return r;
}
static __device__ __forceinline__ float sigm(float x) {
    return __builtin_amdgcn_rcpf(1.0f + __builtin_amdgcn_exp2f(-LOG2E * x));
}
static __device__ __forceinline__ float tanh_(float x) {
    return 1.0f - 2.0f * __builtin_amdgcn_rcpf(1.0f + __builtin_amdgcn_exp2f((2.0f * LOG2E) * x));
}

#define MFMA(A, B, C) __builtin_amdgcn_mfma_f32_16x16x32_bf16((A), (B), (C), 0, 0, 0)

// (Whi + Wlo) * B + Cin, chained accumulate (2 MFMAs, depth 2)
static __device__ __forceinline__ f32x4 side2(short8 Wh, short8 Wl, short8 B,
                                              f32x4 Cin) {
    f32x4 a = MFMA(Wh, B, Cin);
    a = MFMA(Wl, B, a);
    return a;
}

static __device__ __forceinline__ void cvt8(const float* p, short8& h8, short8& l8) {
    f32x4 v0 = *(const f32x4*)p;
    f32x4 v1 = *(const f32x4*)(p + 4);
#pragma unroll
    for (int e = 0; e < 8; ++e) {
        float v = (e < 4) ? v0[e] : v1[e - 4];
        unsigned short hb = f2bf(v);
        h8[e] = (short)hb;
        l8[e] = (short)f2bf(v - bf2f(hb));
    }
}

__global__ __launch_bounds__(512, 1) void gru_fused(
    const float* __restrict__ x,
    const float* __restrict__ Wih0, const float* __restrict__ Whh0,
    const float* __restrict__ bih0, const float* __restrict__ bhh0,
    const float* __restrict__ Wih1, const float* __restrict__ Whh1,
    const float* __restrict__ bih1, const float* __restrict__ bhh1,
    const float* __restrict__ Wfc2, const float* __restrict__ bfc2,
    const float* __restrict__ Wfc,  const float* __restrict__ bfc,
    float* __restrict__ out)
{
    const int tid  = threadIdx.x;
    const int lane = tid & 63;
    const int wid  = tid >> 6;          // 0..7  (SIMD = wid & 3)
    const int role = wid >> 2;          // 0 = main, 1 = helper
    const int L    = (wid >> 1) & 1;    // layer
    const int hf   = wid & 1;           // unit half
    const int c    = lane & 15;         // batch col
    const int q    = lane >> 4;         // 0..3
    const int b0   = blockIdx.x * 16;

    // LDS map:
    //  ST01: h1 frags (L0 state AND L1-helper input), 2 bufs x [16][80B] = 2560
    //  ST2 : h2 frags, 2 bufs x [16][80B]                                = 2560
    //  XS  : x ring, 32 steps x 16 rows x 16B                            = 8192
    //  AX0 : L0 preact, 2 bufs x 6 tiles x 4 q x 16 c x f32x4            = 12288
    //  AX1 : L1 preact, same                                             = 12288
    //  EP  : epilogue scratch                                            = 128
    __shared__ __align__(16) char smem[38016];
    char*  ST01 = smem;
    char*  ST2  = smem + 2560;
    f32x4* XS   = (f32x4*)(smem + 5120);
    f32x4* AX0  = (f32x4*)(smem + 13312);
    f32x4* AX1  = (f32x4*)(smem + 25600);
    float* EP   = (float*)(smem + 37888);

    // zero state buffers (h = 0)
    for (int i = tid; i < 1280; i += 512) ((unsigned*)smem)[i] = 0u;

    // stage x steps 0..31
    if (tid < 256) {
        const int row = tid & 15, so = tid >> 4;
#pragma unroll
        for (int k = 0; k < 2; ++k) {
            const int step = so + 16 * k;
            XS[step * 16 + row] =
                *(const f32x4*)(x + ((long)(b0 + row) * SEQ + step) * 4);
        }
    }

    const int tts[3] = {hf, 2 + hf, 4 + hf};   // r,z,n tiles for this half

    // ------------- per-role weight setup (wave-uniform branches) -----------
    short8 whhh[3], whhl[3];            // mains: Whh hi/lo
    f32x4  bhv2 = {0, 0, 0, 0};        // mains: bhh n-slice (C-in for j=2)
    f32x4  wx0[12];                     // L0 helper: Wih0 rows fp32
    float  bxs[12];                     // L0 helper: folded biases
    short8 wuh[3], wul[3];              // L1 helper: Wih1 hi/lo
    f32x4  bxv[3];                      // L1 helper: folded biases

    if (role == 0) {
        const float* Whp = L ? Whh1 : Whh0;
        const float* bhp = L ? bhh1 : bhh0;
#pragma unroll
        for (int j = 0; j < 3; ++j)
            cvt8(Whp + (16 * tts[j] + c) * 32 + 8 * q, whhh[j], whhl[j]);
        bhv2 = *(const f32x4*)(bhp + 16 * tts[2] + 4 * q);
    } else if (L == 0) {
#pragma unroll
        for (int j = 0; j < 3; ++j)
#pragma unroll
            for (int r = 0; r < 4; ++r) {
                const int g = 16 * tts[j] + 4 * q + r;
                wx0[4 * j + r] = *(const f32x4*)(Wih0 + g * 4);
                bxs[4 * j + r] = bih0[g] + ((j < 2) ? bhh0[g] : 0.0f);
            }
    } else {
#pragma unroll
        for (int j = 0; j < 3; ++j) {
            cvt8(Wih1 + (16 * tts[j] + c) * 32 + 8 * q, wuh[j], wul[j]);
            f32x4 bb = *(const f32x4*)(bih1 + 16 * tts[j] + 4 * q);
            if (j < 2) bb += *(const f32x4*)(bhh1 + 16 * tts[j] + 4 * q);
            bxv[j] = bb;
        }
    }

    // prologue: L0 helper fills AX0 buf0 with step 0 (direct global x read)
    if (role == 1 && L == 0) {
        f32x4 xv = *(const f32x4*)(x + (long)(b0 + c) * (SEQ * 4));
#pragma unroll
        for (int j = 0; j < 3; ++j) {
            f32x4 a;
#pragma unroll
            for (int r = 0; r < 4; ++r) {
                f32x4 w = wx0[4 * j + r];
                a[r] = bxs[4 * j + r] + w[0] * xv[0] + w[1] * xv[1]
                     + w[2] * xv[2] + w[3] * xv[3];
            }
            AX0[tts[j] * 64 + q * 16 + c] = a;
        }
    }

    float hst[4] = {0, 0, 0, 0};   // mains: units 16hf+4q+r, batch c
    f32x4 xr0 = {0, 0, 0, 0}, xr1 = {0, 0, 0, 0};   // T14 staging regs (helpers)
    const int frag_off = c * 80 + q * 16;                 // b128 B-frag read
    const int wr_off   = c * 80 + (16 * hf + 4 * q) * 2;  // b64 D write (hi)

    __syncthreads();

    // ---------------- pipelined main loop: 514 iterations ----------------
    // iter i: L0 main: step i (i<SEQ); reads AX0[i&1], state ST01[(i+1)&1],
    //                  writes h1[i] -> ST01[i&1].
    //         L0 helper: AX0 for step i+1 -> AX0[(i+1)&1]; x staging (T14).
    //         L1 helper: P[i] = Wih1*h1[i-1] (ST01[(i+1)&1]) -> AX1[i&1].
    //         L1 main: step i-2 (i>=2); reads AX1[(i+1)&1], state ST2[(i+1)&1],
    //                  writes h2[i-2] -> ST2[i&1].
#pragma unroll 2
    for (int i = 0; i <= SEQ + 1; ++i) {
        if (role == 0) {
            const bool act = (L == 0) ? (i < SEQ) : (i >= 2);
            if (act) {
                const char*  st;
                const f32x4* axb;
                char*        dst;
                if (L == 0) {
                    st  = ST01 + ((i + 1) & 1) * 1280;
                    axb = AX0 + (i & 1) * 384;
                    dst = ST01 + (i & 1) * 1280;
                } else {
                    st  = ST2 + ((i + 1) & 1) * 1280;
                    axb = AX1 + ((i + 1) & 1) * 384;
                    dst = ST2 + (i & 1) * 1280;
                }
                short8 sfrag = *(const short8*)(st + frag_off);
                f32x4 ax0v = axb[tts[0] * 64 + q * 16 + c];
                f32x4 ax1v = axb[tts[1] * 64 + q * 16 + c];
                f32x4 ax2v = axb[tts[2] * 64 + q * 16 + c];

                f32x4 p0 = side2(whhh[0], whhl[0], sfrag, ax0v);
                f32x4 p1 = side2(whhh[1], whhl[1], sfrag, ax1v);
                f32x4 p2 = side2(whhh[2], whhl[2], sfrag, bhv2);

                float hv[4];
#pragma unroll
                for (int r = 0; r < 4; ++r) {
                    float rg = sigm(p0[r]);
                    float zg = sigm(p1[r]);
                    float ng = tanh_(ax2v[r] + rg * p2[r]);
                    float hN = ng + zg * (hst[r] - ng);
                    hst[r] = hN;
                    hv[r] = hN;
                }
                unsigned w0 = cvtpk(hv[0], hv[1]);
                unsigned w1 = cvtpk(hv[2], hv[3]);
                uint2v wpk = {w0, w1};
                *(uint2v*)(dst + wr_off) = wpk;
            }
        } else if (L == 0) {
            // ---- T14 x staging: issue loads at phase 0, ds_write at phase 8 ----
            if ((i & 15) == 0) {
                const int base = i + 16;
                if (base < SEQ) {
                    const int hidx = tid - 256;          // 0..127
                    const int row = hidx & 15, so = hidx >> 4;
                    xr0 = *(const f32x4*)(x + ((long)(b0 + row) * SEQ + base + so) * 4);
                    xr1 = *(const f32x4*)(x + ((long)(b0 + row) * SEQ + base + so + 8) * 4);
                }
            } else if ((i & 15) == 8) {
                const int base = i + 8;                  // == issue-time base
                if (base < SEQ) {
                    const int hidx = tid - 256;
                    const int row = hidx & 15, so = hidx >> 4;
                    XS[((base + so) & 31) * 16 + row] = xr0;
                    XS[((base + so + 8) & 31) * 16 + row] = xr1;
                }
            }
            // ---- AX0 for step i+1 (exact fp32 x-matvec) ----
            const int step = i + 1;
            if (step < SEQ) {
                f32x4 xv = XS[(step & 31) * 16 + c];
                f32x4* dstax = AX0 + (step & 1) * 384;
#pragma unroll
                for (int j = 0; j < 3; ++j) {
                    f32x4 a;
#pragma unroll
                    for (int r = 0; r < 4; ++r) {
                        f32x4 w = wx0[4 * j + r];
                        a[r] = bxs[4 * j + r] + w[0] * xv[0] + w[1] * xv[1]
                             + w[2] * xv[2] + w[3] * xv[3];
                    }
                    dstax[tts[j] * 64 + q * 16 + c] = a;
                }
            }
        } else {
            // ---- L1 helper: P[i] = Wih1 * h1[i-1] + biases -> AX1[i&1] ----
            if (i >= 1 && i <= SEQ) {
                const char* us = ST01 + ((i + 1) & 1) * 1280;   // h1[i-1]
                short8 uf = *(const short8*)(us + frag_off);
                f32x4* dstax = AX1 + (i & 1) * 384;
#pragma unroll
                for (int j = 0; j < 3; ++j) {
                    f32x4 a = side2(wuh[j], wul[j], uf, bxv[j]);
                    dstax[tts[j] * 64 + q * 16 + c] = a;
                }
            }
        }
        BSYNC();
    }

    // ---------------- epilogue: out = Weff . h2 + cst ----------------
    if (role == 0 && L == 1) {
        float we[4] = {0, 0, 0, 0};
        const float* w2p = Wfc2 + 16 * hf + 4 * q;
#pragma unroll 8
        for (int j = 0; j < 32; ++j) {
            float wf = Wfc[j];
            f32x4 w2 = *(const f32x4*)(w2p + j * 32);
#pragma unroll
            for (int r = 0; r < 4; ++r) we[r] += wf * w2[r];
        }
        float acc = we[0] * hst[0] + we[1] * hst[1] + we[2] * hst[2] + we[3] * hst[3];
        acc += __shfl_xor(acc, 16);
        acc += __shfl_xor(acc, 32);
        if (q == 0) EP[hf * 16 + c] = acc;
    }
    __syncthreads();
    if (wid == 0 && q == 0) {
        float cst = bfc[0];
        for (int j = 0; j < 32; ++j) cst += Wfc[j] * bfc2[j];
        out[b0 + c] = EP[c] + EP[16 + c] + cst;
    }
}

extern "C" void kernel_launch(void* const* d_in, const int* in_sizes, int n_in,
                              void* d_out, int out_size, void* d_ws, size_t ws_size,
                              hipStream_t stream) {
    const float* x    = (const float*)d_in[0];
    const float* Wih0 = (const float*)d_in[1];
    const float* Whh0 = (const float*)d_in[2];
    const float* bih0 = (const float*)d_in[3];
    const float* bhh0 = (const float*)d_in[4];
    const float* Wih1 = (const float*)d_in[5];
    const float* Whh1 = (const float*)d_in[6];
    const float* bih1 = (const float*)d_in[7];
    const float* bhh1 = (const float*)d_in[8];
    const float* Wfc2 = (const float*)d_in[9];
    const float* bfc2 = (const float*)d_in[10];
    const float* Wfc  = (const float*)d_in[11];
    const float* bfc  = (const float*)d_in[12];

    const int nblocks = out_size / 16;  // 4096/16 = 256
    hipLaunchKernelGGL(gru_fused, dim3(nblocks), dim3(512), 0, stream,
                       x, Wih0, Whh0, bih0, bhh0, Wih1, Whh1, bih1, bhh1,
                       Wfc2, bfc2, Wfc, bfc, (float*)d_out);
}